// Round 6
// baseline (137.237 us; speedup 1.0000x reference)
//
#include <hip/hip_runtime.h>
#include <hip/hip_bf16.h>
#include <cstdint>

constexpr int kS  = 384;
constexpr int kB  = 2;
constexpr int kC  = 768;
constexpr int kH  = 12;
constexpr int kCC = 64;
constexpr int kHPB = 4;  // heads per attention block

typedef __attribute__((ext_vector_type(8))) short short8;
typedef __attribute__((ext_vector_type(4))) float f32x4;
typedef __attribute__((ext_vector_type(4))) unsigned short u16x4;
typedef const __attribute__((address_space(1))) unsigned int glb_u32_t;
typedef __attribute__((address_space(3))) unsigned int lds_u32_t;

static __device__ __forceinline__ ushort f2bf(float f) {
  __hip_bfloat16 h = __float2bfloat16(f);
  return *reinterpret_cast<ushort*>(&h);
}

// ---------------------------------------------------------------------------
// One-shot f32 -> bf16 conversion of x, qkv_w, out_w (float4-granular).
// Segments (in float4 units): x 147456 | qkv_w 442368 | out_w 147456.
// ---------------------------------------------------------------------------
__global__ __launch_bounds__(256) void convert_bf16(
    const float* __restrict__ x, const float* __restrict__ qw,
    const float* __restrict__ ow, ushort* __restrict__ xb,
    ushort* __restrict__ qwb, ushort* __restrict__ owb) {
  int idx = blockIdx.x * 256 + threadIdx.x;
  const float* src;
  ushort* dst;
  if (idx < 147456) {
    src = x; dst = xb;
  } else if (idx < 147456 + 442368) {
    idx -= 147456; src = qw; dst = qwb;
  } else {
    idx -= 589824; src = ow; dst = owb;
  }
  f32x4 v = *reinterpret_cast<const f32x4*>(src + (size_t)idx * 4);
  u16x4 o;
  o[0] = f2bf(v[0]); o[1] = f2bf(v[1]); o[2] = f2bf(v[2]); o[3] = f2bf(v[3]);
  *reinterpret_cast<u16x4*>(dst + (size_t)idx * 4) = o;
}

// ---------------------------------------------------------------------------
// MFMA bf16 GEMM, bf16 inputs, global_load_lds staging (width 16).
// Cg[m,n] = sum_k A[m,k]*W[n,k] + bias[n]   (A @ W^T + b), f32 out.
// Tile 64x64, BK=64, 4 waves 2x2, wave tile 32x32 (2x2 16x16x32 frags).
// Swizzle (rule #21): linear LDS dest, source chunk cs = c ^ (r&7),
// ds_read chunk ck ^ (ra&7) -> 2-way banks (free).
// ---------------------------------------------------------------------------
__global__ __launch_bounds__(256) void gemm_bf16_lds(
    const ushort* __restrict__ Abf, const ushort* __restrict__ Wbf,
    const float* __restrict__ bias, float* __restrict__ Cg,
    int M, int N, int K) {
  __shared__ ushort As[64 * 64];
  __shared__ ushort Ws[64 * 64];
  const int tid = threadIdx.x;
  const int m0 = blockIdx.y * 64, n0 = blockIdx.x * 64;
  const int wv = tid >> 6, l = tid & 63;
  const int wr = wv >> 1, wc = wv & 1;
  const int lr = l & 15, lk = l >> 4;

  f32x4 acc[2][2] = {{{0.f, 0.f, 0.f, 0.f}, {0.f, 0.f, 0.f, 0.f}},
                     {{0.f, 0.f, 0.f, 0.f}, {0.f, 0.f, 0.f, 0.f}}};

  for (int k0 = 0; k0 < K; k0 += 64) {
    __syncthreads();  // previous iter's fragment reads must finish
#pragma unroll
    for (int j = 0; j < 2; ++j) {
      int cid = (j * 4 + wv) * 64 + l;     // 16B chunk id, 0..511
      int r = cid >> 3, c = cid & 7;       // row, chunk-in-row
      int cs = c ^ (r & 7);                // inverse-swizzled source chunk
      const ushort* ga = Abf + (size_t)(m0 + r) * K + k0 + cs * 8;
      __builtin_amdgcn_global_load_lds((glb_u32_t*)ga,
                                       (lds_u32_t*)&As[(cid & ~63) * 8],
                                       16, 0, 0);
      const ushort* gw = Wbf + (size_t)(n0 + r) * K + k0 + cs * 8;
      __builtin_amdgcn_global_load_lds((glb_u32_t*)gw,
                                       (lds_u32_t*)&Ws[(cid & ~63) * 8],
                                       16, 0, 0);
    }
    __syncthreads();  // vmcnt(0) drained by compiler before barrier
#pragma unroll
    for (int ks = 0; ks < 2; ++ks) {
      short8 af[2], bw[2];
#pragma unroll
      for (int f = 0; f < 2; ++f) {
        int ra = wr * 32 + f * 16 + lr;
        int ca = (ks * 4 + lk) ^ (ra & 7);  // swizzled read chunk
        af[f] = *reinterpret_cast<const short8*>(&As[(ra * 8 + ca) * 8]);
        int rb = wc * 32 + f * 16 + lr;
        int cb = (ks * 4 + lk) ^ (rb & 7);
        bw[f] = *reinterpret_cast<const short8*>(&Ws[(rb * 8 + cb) * 8]);
      }
#pragma unroll
      for (int fr = 0; fr < 2; ++fr)
#pragma unroll
        for (int fc = 0; fc < 2; ++fc)
          acc[fr][fc] = __builtin_amdgcn_mfma_f32_16x16x32_bf16(
              af[fr], bw[fc], acc[fr][fc], 0, 0, 0);
    }
  }

#pragma unroll
  for (int fr = 0; fr < 2; ++fr)
#pragma unroll
    for (int fc = 0; fc < 2; ++fc)
#pragma unroll
      for (int j = 0; j < 4; ++j) {
        int m = m0 + wr * 32 + fr * 16 + lk * 4 + j;
        int n = n0 + wc * 32 + fc * 16 + lr;
        Cg[(size_t)m * N + n] = acc[fr][fc][j] + bias[n];
      }
}

// ---------------------------------------------------------------------------
// Fused attention: one block per (s, b, head-group-of-4); 256 threads,
// wave = head within group; lane layout: tq = lane>>4, cq = (lane&15)*4.
// Small blocks -> 6 resident blocks/CU -> streaming phases of different
// blocks overlap (HBM stays saturated during softmax/pass2 of others).
// Head groups partition pe's channel axis disjointly: no duplicated traffic.
// ---------------------------------------------------------------------------
__global__ __launch_bounds__(256, 6) void attn_kernel(
    const float* __restrict__ qkv, const float* __restrict__ pe,
    const float* __restrict__ u, const float* __restrict__ w,
    ushort* __restrict__ obf) {
  __shared__ float sc[kHPB][kS];

  const int bid = blockIdx.x;
  const int sb = bid / (kH / kHPB);   // (s,b) index, s-descending
  const int hg = bid % (kH / kHPB);   // head group
  const int s = kS - 1 - (sb >> 1);   // big-s blocks first (load balance)
  const int b = sb & 1;
  const int wave = threadIdx.x >> 6;  // head within group
  const int h = hg * kHPB + wave;
  const int lane = threadIdx.x & 63;
  const int tq = lane >> 4;           // t-subgroup
  const int cq = (lane & 15) * 4;     // channel quad
  const int ch = h * kCC + cq;
  const float scale = 0.125f;         // 1/sqrt(64)

  const int row = s * kB + b;
  const float4 q4 = *(const float4*)&qkv[(int64_t)row * 3 * kC + ch];
  const float4 u4 = *(const float4*)&u[ch];
  const float4 w4 = *(const float4*)&w[ch];
  float4 qu, qw;
  qu.x = q4.x + u4.x; qu.y = q4.y + u4.y; qu.z = q4.z + u4.z; qu.w = q4.w + u4.w;
  qw.x = q4.x + w4.x; qw.y = q4.y + w4.y; qw.z = q4.z + w4.z; qw.w = q4.w + w4.w;

  const float* kbase = qkv + (int64_t)b * 3 * kC + kC + ch;
  const float* vbase = qkv + (int64_t)b * 3 * kC + 2 * kC + ch;
  const float* pbase = pe + ((int64_t)s * kS * kB + b) * kC + ch;
  const int kstride = kB * 3 * kC;  // 4608
  const int pstride = kB * kC;      // 1536

  const int nfull = (s + 1) & ~15;  // t's covered by the unrolled main loop

  // ---- pass 1: scores ----
  int t0 = 0;
  for (; t0 < nfull; t0 += 16) {
    float4 k4[4];
    f32x4 p4[4];
#pragma unroll
    for (int i = 0; i < 4; ++i) {
      int t = t0 + i * 4 + tq;
      k4[i] = *(const float4*)&kbase[(int64_t)t * kstride];
      p4[i] = __builtin_nontemporal_load(
          (const f32x4*)&pbase[(int64_t)t * pstride]);
    }
#pragma unroll
    for (int i = 0; i < 4; ++i) {
      float r = qu.x * k4[i].x + qu.y * k4[i].y + qu.z * k4[i].z +
                qu.w * k4[i].w + qw.x * p4[i][0] + qw.y * p4[i][1] +
                qw.z * p4[i][2] + qw.w * p4[i][3];
      r += __shfl_xor(r, 1);
      r += __shfl_xor(r, 2);
      r += __shfl_xor(r, 4);
      r += __shfl_xor(r, 8);
      if ((lane & 15) == 0) sc[wave][t0 + i * 4 + tq] = r * scale;
    }
  }
  for (; t0 <= s; t0 += 4) {  // tail (<16 t's)
    int t = t0 + tq;
    int tc = (t <= s) ? t : s;  // clamp keeps loads in-bounds
    float4 k4 = *(const float4*)&kbase[(int64_t)tc * kstride];
    float4 p4 = *(const float4*)&pbase[(int64_t)tc * pstride];
    float r = qu.x * k4.x + qu.y * k4.y + qu.z * k4.z + qu.w * k4.w +
              qw.x * p4.x + qw.y * p4.y + qw.z * p4.z + qw.w * p4.w;
    r += __shfl_xor(r, 1);
    r += __shfl_xor(r, 2);
    r += __shfl_xor(r, 4);
    r += __shfl_xor(r, 8);
    if ((lane & 15) == 0 && t <= s) sc[wave][t] = r * scale;
  }
  __syncthreads();

  // ---- softmax over t in [0, s] (wave owns its head's row) ----
  float mx = -1e30f;
  for (int t = lane; t <= s; t += 64) mx = fmaxf(mx, sc[wave][t]);
#pragma unroll
  for (int off = 32; off; off >>= 1) mx = fmaxf(mx, __shfl_xor(mx, off, 64));
  float sum = 0.f;
  for (int t = lane; t <= s; t += 64) {
    float e = __expf(sc[wave][t] - mx);
    sc[wave][t] = e;
    sum += e;
  }
#pragma unroll
  for (int off = 32; off; off >>= 1) sum += __shfl_xor(sum, off, 64);
  const float rden = 1.0f / sum;

  // ---- pass 2: o = p @ v ----
  float4 oa = {0.f, 0.f, 0.f, 0.f};
  t0 = 0;
  for (; t0 < nfull; t0 += 16) {
    float4 v4[4];
    float p[4];
#pragma unroll
    for (int i = 0; i < 4; ++i) {
      int t = t0 + i * 4 + tq;
      v4[i] = *(const float4*)&vbase[(int64_t)t * kstride];
      p[i] = sc[wave][t];
    }
#pragma unroll
    for (int i = 0; i < 4; ++i) {
      oa.x += p[i] * v4[i].x; oa.y += p[i] * v4[i].y;
      oa.z += p[i] * v4[i].z; oa.w += p[i] * v4[i].w;
    }
  }
  for (; t0 <= s; t0 += 4) {  // tail
    int t = t0 + tq;
    if (t <= s) {
      float p = sc[wave][t];
      float4 v4 = *(const float4*)&vbase[(int64_t)t * kstride];
      oa.x += p * v4.x; oa.y += p * v4.y; oa.z += p * v4.z; oa.w += p * v4.w;
    }
  }
#pragma unroll
  for (int off = 16; off <= 32; off <<= 1) {
    oa.x += __shfl_xor(oa.x, off);
    oa.y += __shfl_xor(oa.y, off);
    oa.z += __shfl_xor(oa.z, off);
    oa.w += __shfl_xor(oa.w, off);
  }
  if (lane < 16) {
    u16x4 res;
    res[0] = f2bf(oa.x * rden); res[1] = f2bf(oa.y * rden);
    res[2] = f2bf(oa.z * rden); res[3] = f2bf(oa.w * rden);
    *reinterpret_cast<u16x4*>(&obf[(int64_t)row * kC + ch]) = res;
  }
}

// ---------------------------------------------------------------------------
extern "C" void kernel_launch(void* const* d_in, const int* in_sizes, int n_in,
                              void* d_out, int out_size, void* d_ws,
                              size_t ws_size, hipStream_t stream) {
  const float* x     = (const float*)d_in[0];
  const float* pe    = (const float*)d_in[1];
  // d_in[2] = cm (causal mask, derived analytically), d_in[3] = pm (unused)
  const float* qkv_w = (const float*)d_in[4];
  const float* qkv_b = (const float*)d_in[5];
  const float* u     = (const float*)d_in[6];
  const float* w     = (const float*)d_in[7];
  const float* out_w = (const float*)d_in[8];
  const float* out_b = (const float*)d_in[9];
  float* out = (float*)d_out;

  // workspace layout
  char* wsb = (char*)d_ws;
  float*  qkv  = (float*)wsb;                        // 768x2304 f32 (7.08 MB)
  ushort* xb   = (ushort*)(wsb + 7077888);           // 768x768  bf16
  ushort* qwb  = (ushort*)(wsb + 8257536);           // 2304x768 bf16
  ushort* owb  = (ushort*)(wsb + 11796480);          // 768x768  bf16
  ushort* obf  = (ushort*)(wsb + 12976128);          // 768x768  bf16

  // 1) convert static operands to bf16 (one pass)
  convert_bf16<<<2880, 256, 0, stream>>>(x, qkv_w, out_w, xb, qwb, owb);

  // 2) qkv = x @ qkv_w^T + qkv_b   (M=768, N=2304, K=768)
  gemm_bf16_lds<<<dim3(3 * kC / 64, kS * kB / 64), 256, 0, stream>>>(
      xb, qwb, qkv_b, qkv, kS * kB, 3 * kC, kC);

  // 3) fused attention (causal; only t <= s of pe is ever read)
  attn_kernel<<<kS * kB * (kH / kHPB), kHPB * 64, 0, stream>>>(
      qkv, pe, u, w, obf);

  // 4) out = o @ out_w^T + out_b   (M=768, N=768, K=768)
  gemm_bf16_lds<<<dim3(kC / 64, kS * kB / 64), 256, 0, stream>>>(
      obf, owb, out_b, out, kS * kB, kC, kC);
}